// Round 2
// baseline (574.428 us; speedup 1.0000x reference)
//
#include <hip/hip_runtime.h>

typedef unsigned short u16;
typedef __bf16 bf16x8 __attribute__((ext_vector_type(8)));
typedef float f32x4 __attribute__((ext_vector_type(4)));

__device__ __forceinline__ float b2f(u16 x) {
    unsigned int u = ((unsigned int)x) << 16;
    return __builtin_bit_cast(float, u);
}
__device__ __forceinline__ u16 f2bf(float f) {
    unsigned int u = __builtin_bit_cast(unsigned int, f);
    u += 0x7fffu + ((u >> 16) & 1u);
    return (u16)(u >> 16);
}
__device__ __forceinline__ void lds_load16(const u16* g, u16* l) {
    __builtin_amdgcn_global_load_lds(
        (const __attribute__((address_space(1))) void*)g,
        (__attribute__((address_space(3))) void*)l, 16, 0, 0);
}

// ---------------------------------------------------------------------------
// transpose fp32 -> bf16: out[c][r] = bf16(in[r][c]); R,C multiples of 32
__global__ void transpose_f32_bf16(const float* __restrict__ in, u16* __restrict__ out,
                                   int R, int C) {
    __shared__ u16 tile[32][33];
    int bx = blockIdx.x * 32, by = blockIdx.y * 32;
    int tx = threadIdx.x, ty = threadIdx.y;
#pragma unroll
    for (int i = 0; i < 32; i += 8)
        tile[ty + i][tx] = f2bf(in[(size_t)(by + ty + i) * C + bx + tx]);
    __syncthreads();
#pragma unroll
    for (int i = 0; i < 32; i += 8)
        out[(size_t)(bx + ty + i) * R + by + tx] = tile[tx][ty + i];
}

// elementwise fp32 -> bf16
__global__ void cvt_f32_bf16(const float* __restrict__ in, u16* __restrict__ out, int n) {
    int i = blockIdx.x * 256 + threadIdx.x;
    if (i < n) out[i] = f2bf(in[i]);
}

// ---------------------------------------------------------------------------
// LayerNorm over 1024 cols; fp32 in, bf16 out
__global__ __launch_bounds__(256) void ln_kernel(
    const float* __restrict__ inf, const float* __restrict__ g,
    const float* __restrict__ b, u16* __restrict__ out) {
    int row = blockIdx.x, t = threadIdx.x;
    size_t base = (size_t)row * 1024 + t * 4;
    float4 f = *(const float4*)(inf + base);
    float v[4] = {f.x, f.y, f.z, f.w};
    float s = v[0] + v[1] + v[2] + v[3];
    float q = v[0] * v[0] + v[1] * v[1] + v[2] * v[2] + v[3] * v[3];
#pragma unroll
    for (int m = 1; m < 64; m <<= 1) {
        s += __shfl_xor(s, m);
        q += __shfl_xor(q, m);
    }
    __shared__ float rs[4], rq[4];
    __shared__ float mu_s, rstd_s;
    int w = t >> 6, lane = t & 63;
    if (lane == 0) { rs[w] = s; rq[w] = q; }
    __syncthreads();
    if (t == 0) {
        float S = rs[0] + rs[1] + rs[2] + rs[3];
        float Q2 = rq[0] + rq[1] + rq[2] + rq[3];
        float mu = S * (1.0f / 1024.0f);
        float var = Q2 * (1.0f / 1024.0f) - mu * mu;
        mu_s = mu;
        rstd_s = rsqrtf(var + 1e-5f);
    }
    __syncthreads();
    float mu = mu_s, rstd = rstd_s;
    u16 o[4];
#pragma unroll
    for (int i = 0; i < 4; i++) {
        int col = t * 4 + i;
        o[i] = f2bf((v[i] - mu) * rstd * g[col] + b[col]);
    }
    uint2 pk;
    pk.x = (unsigned)o[0] | ((unsigned)o[1] << 16);
    pk.y = (unsigned)o[2] | ((unsigned)o[3] << 16);
    *(uint2*)(out + base) = pk;
}

// ---------------------------------------------------------------------------
// GEMM: C[M,N] = A[M,K] * Bt[N,K]^T, bf16 in, fp32 acc.
// Epilogue: (+bias fp32)*oscale, optional GELU(erf), optional fp32 residual,
// bf16 and/or fp32 out. Bt row index clamped to nclamp-1 (padded-N rel GEMM).
__global__ __launch_bounds__(256) void gemm_bt(
    const u16* __restrict__ A, int lda, long long sAz,
    const u16* __restrict__ Bt, int ldb, long long sBz, int nclamp,
    const float* __restrict__ bias,
    const float* __restrict__ resid_f32,
    u16* __restrict__ outb, float* __restrict__ outf, int ldc, long long sCz,
    int K, float oscale, int gelu) {
    __shared__ __align__(16) u16 As[128 * 32];
    __shared__ __align__(16) u16 Bs[128 * 32];
    int t = threadIdx.x, w = t >> 6, lane = t & 63;
    int z = blockIdx.z;
    const u16* Ab = A + (size_t)z * sAz;
    const u16* Bb = Bt + (size_t)z * sBz;
    int m0 = blockIdx.y * 128, n0 = blockIdx.x * 128;
    int lo = lane & 15, hi = lane >> 4;
    int wr = w >> 1, wc = w & 1;
    bool isA = (w < 2);
    int part = isA ? w : (w - 2);
    f32x4 acc[4][4];
#pragma unroll
    for (int i = 0; i < 4; i++)
#pragma unroll
        for (int j = 0; j < 4; j++) acc[i][j] = (f32x4){0.f, 0.f, 0.f, 0.f};

    for (int k0 = 0; k0 < K; k0 += 32) {
#pragma unroll
        for (int cc = 0; cc < 4; ++cc) {
            int slot = (part * 4 + cc) * 64 + lane;  // 0..511
            int row = slot >> 2, c8 = (slot & 3) * 8;
            if (isA) {
                const u16* gp = Ab + (size_t)(m0 + row) * lda + k0 + c8;
                lds_load16(gp, &As[(part * 4 + cc) * 512]);
            } else {
                int n = n0 + row;
                if (n >= nclamp) n = nclamp - 1;
                const u16* gp = Bb + (size_t)n * ldb + k0 + c8;
                lds_load16(gp, &Bs[(part * 4 + cc) * 512]);
            }
        }
        __syncthreads();
        bf16x8 a[4], bb[4];
#pragma unroll
        for (int i = 0; i < 4; i++)
            a[i] = *(const bf16x8*)&As[(wr * 64 + i * 16 + lo) * 32 + 8 * hi];
#pragma unroll
        for (int j = 0; j < 4; j++)
            bb[j] = *(const bf16x8*)&Bs[(wc * 64 + j * 16 + lo) * 32 + 8 * hi];
#pragma unroll
        for (int i = 0; i < 4; i++)
#pragma unroll
            for (int j = 0; j < 4; j++)
                acc[i][j] = __builtin_amdgcn_mfma_f32_16x16x32_bf16(a[i], bb[j], acc[i][j], 0, 0, 0);
        __syncthreads();
    }
    // epilogue
#pragma unroll
    for (int j = 0; j < 4; j++) {
        int col = n0 + wc * 64 + j * 16 + lo;
        float bv = bias ? bias[col] : 0.f;
#pragma unroll
        for (int i = 0; i < 4; i++) {
            int rbase = m0 + wr * 64 + i * 16 + hi * 4;
#pragma unroll
            for (int r = 0; r < 4; r++) {
                float v = (acc[i][j][r] + bv) * oscale;
                if (gelu) v = 0.5f * v * (1.f + erff(v * 0.70710678118654752f));
                size_t ridx = (size_t)(rbase + r) * ldc + col;
                if (resid_f32) v += resid_f32[ridx];
                size_t idx = (size_t)z * sCz + ridx;
                if (outf) outf[idx] = v;
                if (outb) outb[idx] = f2bf(v);
            }
        }
    }
}

// ---------------------------------------------------------------------------
// Flash attention with rel-pos bias gathered from precomputed Qrel.
// Block = (b, h, q-block of 64); 4 waves x 16 q rows; K/V chunks of 64.
#define QREL_LD 384
__global__ __launch_bounds__(256) void attn_kernel(
    const u16* __restrict__ Qb, const u16* __restrict__ Kb,
    const u16* __restrict__ Vb, const u16* __restrict__ Qrel,
    u16* __restrict__ Ob) {
    __shared__ __align__(16) u16 Ks[64 * 72];
    __shared__ __align__(16) u16 Vt[64 * 72];
    __shared__ __align__(16) u16 Ps[4][16 * 72];
    int t = threadIdx.x, w = t >> 6, lane = t & 63;
    int bid = blockIdx.x;
    int qblk = bid & 15, h = (bid >> 4) & 15, bb = bid >> 8;
    int lo = lane & 15, hi = lane >> 4;
    int q0 = qblk * 64 + w * 16;

    const u16* qrow = Qb + ((size_t)(bb * 1024 + q0 + lo) * 1024 + h * 64 + hi * 8);
    bf16x8 qf0 = *(const bf16x8*)qrow;
    bf16x8 qf1 = *(const bf16x8*)(qrow + 32);

    f32x4 oacc[4];
#pragma unroll
    for (int j = 0; j < 4; j++) oacc[j] = (f32x4){0.f, 0.f, 0.f, 0.f};
    float m_[4] = {-1e30f, -1e30f, -1e30f, -1e30f};
    float l_[4] = {0.f, 0.f, 0.f, 0.f};
    const size_t qrel_base = (size_t)h * (4096ull * QREL_LD);

    for (int c = 0; c < 16; ++c) {
        int k0 = c * 64;
        __syncthreads();  // previous chunk's LDS reads done
#pragma unroll
        for (int i = 0; i < 2; i++) {
            int slot = t + 256 * i;  // 0..511
            int kr = slot >> 3, d8 = (slot & 7) * 8;
            size_t gb = (size_t)(bb * 1024 + k0 + kr) * 1024 + h * 64 + d8;
            uint4 kd = *(const uint4*)(Kb + gb);
            *(uint4*)(&Ks[kr * 72 + d8]) = kd;
            uint4 vd = *(const uint4*)(Vb + gb);
            const u16* pv = (const u16*)&vd;
#pragma unroll
            for (int jj = 0; jj < 8; jj++) Vt[(d8 + jj) * 72 + kr] = pv[jj];
        }
        __syncthreads();  // staging visible

        f32x4 sc[4];
#pragma unroll
        for (int kt = 0; kt < 4; kt++) {
            bf16x8 kf0 = *(const bf16x8*)&Ks[(kt * 16 + lo) * 72 + 8 * hi];
            bf16x8 kf1 = *(const bf16x8*)&Ks[(kt * 16 + lo) * 72 + 32 + 8 * hi];
            f32x4 zz = (f32x4){0.f, 0.f, 0.f, 0.f};
            sc[kt] = __builtin_amdgcn_mfma_f32_16x16x32_bf16(qf0, kf0, zz, 0, 0, 0);
            sc[kt] = __builtin_amdgcn_mfma_f32_16x16x32_bf16(qf1, kf1, sc[kt], 0, 0, 0);
        }
        // rel-pos bias gather (Q was pre-scaled by 1/8, so no extra scale)
#pragma unroll
        for (int kt = 0; kt < 4; kt++)
#pragma unroll
            for (int r = 0; r < 4; r++) {
                int q = q0 + hi * 4 + r;
                int k = k0 + kt * 16 + lo;
                int p = k - q;
                p = p < -128 ? -128 : (p > 128 ? 128 : p);
                p += 128;
                sc[kt][r] += b2f(Qrel[qrel_base + (size_t)(bb * 1024 + q) * QREL_LD + p]);
            }
        // online softmax (rows live on 16-lane groups)
        float alpha[4];
#pragma unroll
        for (int r = 0; r < 4; r++) {
            float cm = fmaxf(fmaxf(sc[0][r], sc[1][r]), fmaxf(sc[2][r], sc[3][r]));
#pragma unroll
            for (int m = 1; m < 16; m <<= 1) cm = fmaxf(cm, __shfl_xor(cm, m));
            float nm = fmaxf(m_[r], cm);
            alpha[r] = __expf(m_[r] - nm);
            m_[r] = nm;
            float rsum = 0.f;
#pragma unroll
            for (int kt = 0; kt < 4; kt++) {
                sc[kt][r] = __expf(sc[kt][r] - nm);
                rsum += sc[kt][r];
            }
#pragma unroll
            for (int m = 1; m < 16; m <<= 1) rsum += __shfl_xor(rsum, m);
            l_[r] = l_[r] * alpha[r] + rsum;
        }
#pragma unroll
        for (int j = 0; j < 4; j++)
#pragma unroll
            for (int r = 0; r < 4; r++) oacc[j][r] *= alpha[r];
        // P: C-layout -> LDS -> A-layout
#pragma unroll
        for (int kt = 0; kt < 4; kt++)
#pragma unroll
            for (int r = 0; r < 4; r++)
                Ps[w][(hi * 4 + r) * 72 + kt * 16 + lo] = f2bf(sc[kt][r]);
        __syncthreads();  // Ps write -> read safety
        bf16x8 pf0 = *(const bf16x8*)&Ps[w][lo * 72 + 8 * hi];
        bf16x8 pf1 = *(const bf16x8*)&Ps[w][lo * 72 + 32 + 8 * hi];
#pragma unroll
        for (int j = 0; j < 4; j++) {
            bf16x8 vf0 = *(const bf16x8*)&Vt[(j * 16 + lo) * 72 + 8 * hi];
            bf16x8 vf1 = *(const bf16x8*)&Vt[(j * 16 + lo) * 72 + 32 + 8 * hi];
            oacc[j] = __builtin_amdgcn_mfma_f32_16x16x32_bf16(pf0, vf0, oacc[j], 0, 0, 0);
            oacc[j] = __builtin_amdgcn_mfma_f32_16x16x32_bf16(pf1, vf1, oacc[j], 0, 0, 0);
        }
    }
#pragma unroll
    for (int r = 0; r < 4; r++) {
        float inv = 1.f / l_[r];
        int q = q0 + hi * 4 + r;
#pragma unroll
        for (int j = 0; j < 4; j++)
            Ob[(size_t)(bb * 1024 + q) * 1024 + h * 64 + j * 16 + lo] =
                f2bf(oacc[j][r] * inv);
    }
}

// ---------------------------------------------------------------------------
extern "C" void kernel_launch(void* const* d_in, const int* in_sizes, int n_in,
                              void* d_out, int out_size, void* d_ws, size_t ws_size,
                              hipStream_t stream) {
    const float* x   = (const float*)d_in[0];
    const float* wq  = (const float*)d_in[1];
    const float* bq  = (const float*)d_in[2];
    const float* wk  = (const float*)d_in[3];
    const float* bk  = (const float*)d_in[4];
    const float* wv  = (const float*)d_in[5];
    const float* bv  = (const float*)d_in[6];
    const float* wo  = (const float*)d_in[7];
    const float* bo  = (const float*)d_in[8];
    const float* rel = (const float*)d_in[9];
    const float* g1  = (const float*)d_in[10];
    const float* be1 = (const float*)d_in[11];
    const float* g2  = (const float*)d_in[12];
    const float* be2 = (const float*)d_in[13];
    const float* w1  = (const float*)d_in[14];
    const float* bf1 = (const float*)d_in[15];
    const float* w2  = (const float*)d_in[16];
    const float* bf2 = (const float*)d_in[17];

    char* ws = (char*)d_ws;
    const size_t MB = 1024ull * 1024ull;
    u16* wqT  = (u16*)(ws + 0 * MB);     // [1024][1024] bf16
    u16* wkT  = (u16*)(ws + 2 * MB);
    u16* wvT  = (u16*)(ws + 4 * MB);
    u16* woT  = (u16*)(ws + 6 * MB);
    u16* w1T  = (u16*)(ws + 8 * MB);     // [4096][1024] bf16
    u16* w2T  = (u16*)(ws + 16 * MB);    // [1024][4096] bf16
    u16* h    = (u16*)(ws + 24 * MB);    // LN1 out, later LN2 out
    u16* Qb   = (u16*)(ws + 32 * MB);
    u16* Kb   = (u16*)(ws + 40 * MB);
    u16* Vb   = (u16*)(ws + 48 * MB);
    u16* qrel = (u16*)(ws + 56 * MB);    // [16][4096][384] bf16 = 48MB
    u16* att  = (u16*)(ws + 104 * MB);
    float* x2 = (float*)(ws + 112 * MB); // fp32 [4096][1024] = 16MB -> 128MB total
    u16* relb = (u16*)(ws + 112 * MB);   // [257][64] bf16, dead before x2 written
    u16* ff1  = (u16*)(ws + 32 * MB);    // aliases Q/K/V + qrel head (dead post-attn)
    u16* h2   = h;

    dim3 tb(32, 8);
    transpose_f32_bf16<<<dim3(32, 32), tb, 0, stream>>>(wq, wqT, 1024, 1024);
    transpose_f32_bf16<<<dim3(32, 32), tb, 0, stream>>>(wk, wkT, 1024, 1024);
    transpose_f32_bf16<<<dim3(32, 32), tb, 0, stream>>>(wv, wvT, 1024, 1024);
    transpose_f32_bf16<<<dim3(32, 32), tb, 0, stream>>>(wo, woT, 1024, 1024);
    transpose_f32_bf16<<<dim3(128, 32), tb, 0, stream>>>(w1, w1T, 1024, 4096);
    transpose_f32_bf16<<<dim3(32, 128), tb, 0, stream>>>(w2, w2T, 4096, 1024);
    cvt_f32_bf16<<<65, 256, 0, stream>>>(rel, relb, 257 * 64);

    ln_kernel<<<4096, 256, 0, stream>>>(x, g1, be1, h);

    // Q pre-scaled by 1/sqrt(HD)=0.125 (exact in bf16)
    gemm_bt<<<dim3(8, 32, 1), 256, 0, stream>>>(h, 1024, 0, wqT, 1024, 0, 1024,
        bq, nullptr, Qb, nullptr, 1024, 0, 1024, 0.125f, 0);
    gemm_bt<<<dim3(8, 32, 1), 256, 0, stream>>>(h, 1024, 0, wkT, 1024, 0, 1024,
        bk, nullptr, Kb, nullptr, 1024, 0, 1024, 1.f, 0);
    gemm_bt<<<dim3(8, 32, 1), 256, 0, stream>>>(h, 1024, 0, wvT, 1024, 0, 1024,
        bv, nullptr, Vb, nullptr, 1024, 0, 1024, 1.f, 0);

    // Qrel[h, b*s, p] = Q[:, h*64:+64] @ rel^T   (N=257 padded to 384)
    gemm_bt<<<dim3(3, 32, 16), 256, 0, stream>>>(Qb, 1024, 64, relb, 64, 0, 257,
        nullptr, nullptr, qrel, nullptr, QREL_LD, (long long)4096 * QREL_LD,
        64, 1.f, 0);

    attn_kernel<<<1024, 256, 0, stream>>>(Qb, Kb, Vb, qrel, att);

    // x2 = x + attn @ wo + bo   (fp32)
    gemm_bt<<<dim3(8, 32, 1), 256, 0, stream>>>(att, 1024, 0, woT, 1024, 0, 1024,
        bo, x, nullptr, x2, 1024, 0, 1024, 1.f, 0);

    ln_kernel<<<4096, 256, 0, stream>>>(x2, g2, be2, h2);

    // ff1 = gelu(h2 @ w1 + b1)
    gemm_bt<<<dim3(32, 32, 1), 256, 0, stream>>>(h2, 1024, 0, w1T, 1024, 0, 4096,
        bf1, nullptr, ff1, nullptr, 4096, 0, 1024, 1.f, 1);
    // out = x2 + ff1 @ w2 + b2
    gemm_bt<<<dim3(8, 32, 1), 256, 0, stream>>>(ff1, 4096, 0, w2T, 4096, 0, 1024,
        bf2, x2, nullptr, (float*)d_out, 1024, 0, 4096, 1.f, 0);
}

// Round 3
// 522.629 us; speedup vs baseline: 1.0991x; 1.0991x over previous
//
#include <hip/hip_runtime.h>

typedef unsigned short u16;
typedef __bf16 bf16x8 __attribute__((ext_vector_type(8)));
typedef float f32x4 __attribute__((ext_vector_type(4)));

__device__ __forceinline__ float b2f(u16 x) {
    unsigned int u = ((unsigned int)x) << 16;
    return __builtin_bit_cast(float, u);
}
__device__ __forceinline__ u16 f2bf(float f) {
    unsigned int u = __builtin_bit_cast(unsigned int, f);
    u += 0x7fffu + ((u >> 16) & 1u);
    return (u16)(u >> 16);
}
__device__ __forceinline__ void lds_load16(const u16* g, u16* l) {
    __builtin_amdgcn_global_load_lds(
        (const __attribute__((address_space(1))) void*)g,
        (__attribute__((address_space(3))) void*)l, 16, 0, 0);
}

// ---------------------------------------------------------------------------
// transpose fp32 -> bf16: out[c][r] = bf16(in[r][c]); R,C multiples of 32
__global__ void transpose_f32_bf16(const float* __restrict__ in, u16* __restrict__ out,
                                   int R, int C) {
    __shared__ u16 tile[32][33];
    int bx = blockIdx.x * 32, by = blockIdx.y * 32;
    int tx = threadIdx.x, ty = threadIdx.y;
#pragma unroll
    for (int i = 0; i < 32; i += 8)
        tile[ty + i][tx] = f2bf(in[(size_t)(by + ty + i) * C + bx + tx]);
    __syncthreads();
#pragma unroll
    for (int i = 0; i < 32; i += 8)
        out[(size_t)(bx + ty + i) * R + by + tx] = tile[tx][ty + i];
}

// elementwise fp32 -> bf16
__global__ void cvt_f32_bf16(const float* __restrict__ in, u16* __restrict__ out, int n) {
    int i = blockIdx.x * 256 + threadIdx.x;
    if (i < n) out[i] = f2bf(in[i]);
}

// ---------------------------------------------------------------------------
// LayerNorm over 1024 cols; fp32 in, bf16 out
__global__ __launch_bounds__(256) void ln_kernel(
    const float* __restrict__ inf, const float* __restrict__ g,
    const float* __restrict__ b, u16* __restrict__ out) {
    int row = blockIdx.x, t = threadIdx.x;
    size_t base = (size_t)row * 1024 + t * 4;
    float4 f = *(const float4*)(inf + base);
    float v[4] = {f.x, f.y, f.z, f.w};
    float s = v[0] + v[1] + v[2] + v[3];
    float q = v[0] * v[0] + v[1] * v[1] + v[2] * v[2] + v[3] * v[3];
#pragma unroll
    for (int m = 1; m < 64; m <<= 1) {
        s += __shfl_xor(s, m);
        q += __shfl_xor(q, m);
    }
    __shared__ float rs[4], rq[4];
    __shared__ float mu_s, rstd_s;
    int w = t >> 6, lane = t & 63;
    if (lane == 0) { rs[w] = s; rq[w] = q; }
    __syncthreads();
    if (t == 0) {
        float S = rs[0] + rs[1] + rs[2] + rs[3];
        float Q2 = rq[0] + rq[1] + rq[2] + rq[3];
        float mu = S * (1.0f / 1024.0f);
        float var = Q2 * (1.0f / 1024.0f) - mu * mu;
        mu_s = mu;
        rstd_s = rsqrtf(var + 1e-5f);
    }
    __syncthreads();
    float mu = mu_s, rstd = rstd_s;
    u16 o[4];
#pragma unroll
    for (int i = 0; i < 4; i++) {
        int col = t * 4 + i;
        o[i] = f2bf((v[i] - mu) * rstd * g[col] + b[col]);
    }
    uint2 pk;
    pk.x = (unsigned)o[0] | ((unsigned)o[1] << 16);
    pk.y = (unsigned)o[2] | ((unsigned)o[3] << 16);
    *(uint2*)(out + base) = pk;
}

// ---------------------------------------------------------------------------
// GEMM: C[M,N] = A[M,K] * Bt[N,K]^T, bf16 in, fp32 acc. Double-buffered LDS:
// one barrier per K-step, prefetch issued after the barrier so the drain at
// the NEXT barrier overlaps with this step's compute.
// Epilogue: (+bias fp32)*oscale, optional GELU(erf), optional fp32 residual,
// bf16 and/or fp32 out. Bt row index clamped to nclamp-1 (padded-N rel GEMM).
__global__ __launch_bounds__(256) void gemm_bt(
    const u16* __restrict__ A, int lda, long long sAz,
    const u16* __restrict__ Bt, int ldb, long long sBz, int nclamp,
    const float* __restrict__ bias,
    const float* __restrict__ resid_f32,
    u16* __restrict__ outb, float* __restrict__ outf, int ldc, long long sCz,
    int K, float oscale, int gelu) {
    __shared__ __align__(16) u16 As[2][128 * 32];
    __shared__ __align__(16) u16 Bs[2][128 * 32];
    int t = threadIdx.x, w = t >> 6, lane = t & 63;
    int z = blockIdx.z;
    const u16* Ab = A + (size_t)z * sAz;
    const u16* Bb = Bt + (size_t)z * sBz;
    int m0 = blockIdx.y * 128, n0 = blockIdx.x * 128;
    int lo = lane & 15, hi = lane >> 4;
    int wr = w >> 1, wc = w & 1;
    bool isA = (w < 2);
    int part = isA ? w : (w - 2);
    f32x4 acc[4][4];
#pragma unroll
    for (int i = 0; i < 4; i++)
#pragma unroll
        for (int j = 0; j < 4; j++) acc[i][j] = (f32x4){0.f, 0.f, 0.f, 0.f};

    auto stage = [&](int k0, int buf) {
#pragma unroll
        for (int cc = 0; cc < 4; ++cc) {
            int slot = (part * 4 + cc) * 64 + lane;  // 0..511
            int row = slot >> 2, c8 = (slot & 3) * 8;
            if (isA) {
                const u16* gp = Ab + (size_t)(m0 + row) * lda + k0 + c8;
                lds_load16(gp, &As[buf][(part * 4 + cc) * 512]);
            } else {
                int n = n0 + row;
                if (n >= nclamp) n = nclamp - 1;
                const u16* gp = Bb + (size_t)n * ldb + k0 + c8;
                lds_load16(gp, &Bs[buf][(part * 4 + cc) * 512]);
            }
        }
    };

    int nk = K >> 5;
    stage(0, 0);
    for (int kk = 0; kk < nk; ++kk) {
        __syncthreads();  // drains this step's loads (in flight since prev step)
        if (kk + 1 < nk) stage((kk + 1) << 5, (kk + 1) & 1);
        int buf = kk & 1;
        bf16x8 a[4], bb[4];
#pragma unroll
        for (int i = 0; i < 4; i++)
            a[i] = *(const bf16x8*)&As[buf][(wr * 64 + i * 16 + lo) * 32 + 8 * hi];
#pragma unroll
        for (int j = 0; j < 4; j++)
            bb[j] = *(const bf16x8*)&Bs[buf][(wc * 64 + j * 16 + lo) * 32 + 8 * hi];
#pragma unroll
        for (int i = 0; i < 4; i++)
#pragma unroll
            for (int j = 0; j < 4; j++)
                acc[i][j] = __builtin_amdgcn_mfma_f32_16x16x32_bf16(a[i], bb[j], acc[i][j], 0, 0, 0);
    }
    // epilogue
#pragma unroll
    for (int j = 0; j < 4; j++) {
        int col = n0 + wc * 64 + j * 16 + lo;
        float bv = bias ? bias[col] : 0.f;
#pragma unroll
        for (int i = 0; i < 4; i++) {
            int rbase = m0 + wr * 64 + i * 16 + hi * 4;
#pragma unroll
            for (int r = 0; r < 4; r++) {
                float v = (acc[i][j][r] + bv) * oscale;
                if (gelu) v = 0.5f * v * (1.f + erff(v * 0.70710678118654752f));
                size_t ridx = (size_t)(rbase + r) * ldc + col;
                if (resid_f32) v += resid_f32[ridx];
                size_t idx = (size_t)z * sCz + ridx;
                if (outf) outf[idx] = v;
                if (outb) outb[idx] = f2bf(v);
            }
        }
    }
}

// ---------------------------------------------------------------------------
// Flash attention with rel-pos bias gathered from precomputed Qrel.
// Block = (b, h, q-block of 64); 4 waves x 16 q rows; K/V chunks of 64.
#define QREL_LD 384
__global__ __launch_bounds__(256) void attn_kernel(
    const u16* __restrict__ Qb, const u16* __restrict__ Kb,
    const u16* __restrict__ Vb, const u16* __restrict__ Qrel,
    u16* __restrict__ Ob) {
    __shared__ __align__(16) u16 Ks[64 * 72];
    __shared__ __align__(16) u16 Vt[64 * 72];
    __shared__ __align__(16) u16 Ps[4][16 * 72];
    int t = threadIdx.x, w = t >> 6, lane = t & 63;
    int bid = blockIdx.x;
    int qblk = bid & 15, h = (bid >> 4) & 15, bb = bid >> 8;
    int lo = lane & 15, hi = lane >> 4;
    int q0 = qblk * 64 + w * 16;

    const u16* qrow = Qb + ((size_t)(bb * 1024 + q0 + lo) * 1024 + h * 64 + hi * 8);
    bf16x8 qf0 = *(const bf16x8*)qrow;
    bf16x8 qf1 = *(const bf16x8*)(qrow + 32);

    f32x4 oacc[4];
#pragma unroll
    for (int j = 0; j < 4; j++) oacc[j] = (f32x4){0.f, 0.f, 0.f, 0.f};
    float m_[4] = {-1e30f, -1e30f, -1e30f, -1e30f};
    float l_[4] = {0.f, 0.f, 0.f, 0.f};
    const size_t qrel_base = (size_t)h * (4096ull * QREL_LD);

    for (int c = 0; c < 16; ++c) {
        int k0 = c * 64;
        __syncthreads();  // previous chunk's LDS reads done
#pragma unroll
        for (int i = 0; i < 2; i++) {
            int slot = t + 256 * i;  // 0..511
            int kr = slot >> 3, d8 = (slot & 7) * 8;
            size_t gb = (size_t)(bb * 1024 + k0 + kr) * 1024 + h * 64 + d8;
            uint4 kd = *(const uint4*)(Kb + gb);
            *(uint4*)(&Ks[kr * 72 + d8]) = kd;
            uint4 vd = *(const uint4*)(Vb + gb);
            const u16* pv = (const u16*)&vd;
#pragma unroll
            for (int jj = 0; jj < 8; jj++) Vt[(d8 + jj) * 72 + kr] = pv[jj];
        }
        __syncthreads();  // staging visible

        f32x4 sc[4];
#pragma unroll
        for (int kt = 0; kt < 4; kt++) {
            bf16x8 kf0 = *(const bf16x8*)&Ks[(kt * 16 + lo) * 72 + 8 * hi];
            bf16x8 kf1 = *(const bf16x8*)&Ks[(kt * 16 + lo) * 72 + 32 + 8 * hi];
            f32x4 zz = (f32x4){0.f, 0.f, 0.f, 0.f};
            sc[kt] = __builtin_amdgcn_mfma_f32_16x16x32_bf16(qf0, kf0, zz, 0, 0, 0);
            sc[kt] = __builtin_amdgcn_mfma_f32_16x16x32_bf16(qf1, kf1, sc[kt], 0, 0, 0);
        }
        // rel-pos bias gather (Q was pre-scaled by 1/8, so no extra scale)
#pragma unroll
        for (int kt = 0; kt < 4; kt++)
#pragma unroll
            for (int r = 0; r < 4; r++) {
                int q = q0 + hi * 4 + r;
                int k = k0 + kt * 16 + lo;
                int p = k - q;
                p = p < -128 ? -128 : (p > 128 ? 128 : p);
                p += 128;
                sc[kt][r] += b2f(Qrel[qrel_base + (size_t)(bb * 1024 + q) * QREL_LD + p]);
            }
        // online softmax (rows live on 16-lane groups)
        float alpha[4];
#pragma unroll
        for (int r = 0; r < 4; r++) {
            float cm = fmaxf(fmaxf(sc[0][r], sc[1][r]), fmaxf(sc[2][r], sc[3][r]));
#pragma unroll
            for (int m = 1; m < 16; m <<= 1) cm = fmaxf(cm, __shfl_xor(cm, m));
            float nm = fmaxf(m_[r], cm);
            alpha[r] = __expf(m_[r] - nm);
            m_[r] = nm;
            float rsum = 0.f;
#pragma unroll
            for (int kt = 0; kt < 4; kt++) {
                sc[kt][r] = __expf(sc[kt][r] - nm);
                rsum += sc[kt][r];
            }
#pragma unroll
            for (int m = 1; m < 16; m <<= 1) rsum += __shfl_xor(rsum, m);
            l_[r] = l_[r] * alpha[r] + rsum;
        }
#pragma unroll
        for (int j = 0; j < 4; j++)
#pragma unroll
            for (int r = 0; r < 4; r++) oacc[j][r] *= alpha[r];
        // P: C-layout -> LDS -> A-layout
#pragma unroll
        for (int kt = 0; kt < 4; kt++)
#pragma unroll
            for (int r = 0; r < 4; r++)
                Ps[w][(hi * 4 + r) * 72 + kt * 16 + lo] = f2bf(sc[kt][r]);
        __syncthreads();  // Ps write -> read safety
        bf16x8 pf0 = *(const bf16x8*)&Ps[w][lo * 72 + 8 * hi];
        bf16x8 pf1 = *(const bf16x8*)&Ps[w][lo * 72 + 32 + 8 * hi];
#pragma unroll
        for (int j = 0; j < 4; j++) {
            bf16x8 vf0 = *(const bf16x8*)&Vt[(j * 16 + lo) * 72 + 8 * hi];
            bf16x8 vf1 = *(const bf16x8*)&Vt[(j * 16 + lo) * 72 + 32 + 8 * hi];
            oacc[j] = __builtin_amdgcn_mfma_f32_16x16x32_bf16(pf0, vf0, oacc[j], 0, 0, 0);
            oacc[j] = __builtin_amdgcn_mfma_f32_16x16x32_bf16(pf1, vf1, oacc[j], 0, 0, 0);
        }
    }
#pragma unroll
    for (int r = 0; r < 4; r++) {
        float inv = 1.f / l_[r];
        int q = q0 + hi * 4 + r;
#pragma unroll
        for (int j = 0; j < 4; j++)
            Ob[(size_t)(bb * 1024 + q) * 1024 + h * 64 + j * 16 + lo] =
                f2bf(oacc[j][r] * inv);
    }
}

// ---------------------------------------------------------------------------
extern "C" void kernel_launch(void* const* d_in, const int* in_sizes, int n_in,
                              void* d_out, int out_size, void* d_ws, size_t ws_size,
                              hipStream_t stream) {
    const float* x   = (const float*)d_in[0];
    const float* wq  = (const float*)d_in[1];
    const float* bq  = (const float*)d_in[2];
    const float* wk  = (const float*)d_in[3];
    const float* bk  = (const float*)d_in[4];
    const float* wv  = (const float*)d_in[5];
    const float* bv  = (const float*)d_in[6];
    const float* wo  = (const float*)d_in[7];
    const float* bo  = (const float*)d_in[8];
    const float* rel = (const float*)d_in[9];
    const float* g1  = (const float*)d_in[10];
    const float* be1 = (const float*)d_in[11];
    const float* g2  = (const float*)d_in[12];
    const float* be2 = (const float*)d_in[13];
    const float* w1  = (const float*)d_in[14];
    const float* bf1 = (const float*)d_in[15];
    const float* w2  = (const float*)d_in[16];
    const float* bf2 = (const float*)d_in[17];

    char* ws = (char*)d_ws;
    const size_t MB = 1024ull * 1024ull;
    u16* wqT  = (u16*)(ws + 0 * MB);     // [1024][1024] bf16
    u16* wkT  = (u16*)(ws + 2 * MB);
    u16* wvT  = (u16*)(ws + 4 * MB);
    u16* woT  = (u16*)(ws + 6 * MB);
    u16* w1T  = (u16*)(ws + 8 * MB);     // [4096][1024] bf16
    u16* w2T  = (u16*)(ws + 16 * MB);    // [1024][4096] bf16
    u16* h    = (u16*)(ws + 24 * MB);    // LN1 out, later LN2 out
    u16* Qb   = (u16*)(ws + 32 * MB);
    u16* Kb   = (u16*)(ws + 40 * MB);
    u16* Vb   = (u16*)(ws + 48 * MB);
    u16* qrel = (u16*)(ws + 56 * MB);    // [16][4096][384] bf16 = 48MB
    u16* att  = (u16*)(ws + 104 * MB);
    float* x2 = (float*)(ws + 112 * MB); // fp32 [4096][1024] = 16MB -> 128MB total
    u16* relb = (u16*)(ws + 112 * MB);   // [257][64] bf16, dead before x2 written
    u16* ff1  = (u16*)(ws + 32 * MB);    // aliases Q/K/V + qrel head (dead post-attn)
    u16* h2   = h;

    dim3 tb(32, 8);
    transpose_f32_bf16<<<dim3(32, 32), tb, 0, stream>>>(wq, wqT, 1024, 1024);
    transpose_f32_bf16<<<dim3(32, 32), tb, 0, stream>>>(wk, wkT, 1024, 1024);
    transpose_f32_bf16<<<dim3(32, 32), tb, 0, stream>>>(wv, wvT, 1024, 1024);
    transpose_f32_bf16<<<dim3(32, 32), tb, 0, stream>>>(wo, woT, 1024, 1024);
    transpose_f32_bf16<<<dim3(128, 32), tb, 0, stream>>>(w1, w1T, 1024, 4096);
    transpose_f32_bf16<<<dim3(32, 128), tb, 0, stream>>>(w2, w2T, 4096, 1024);
    cvt_f32_bf16<<<65, 256, 0, stream>>>(rel, relb, 257 * 64);

    ln_kernel<<<4096, 256, 0, stream>>>(x, g1, be1, h);

    // Q pre-scaled by 1/sqrt(HD)=0.125 (exact in bf16)
    gemm_bt<<<dim3(8, 32, 1), 256, 0, stream>>>(h, 1024, 0, wqT, 1024, 0, 1024,
        bq, nullptr, Qb, nullptr, 1024, 0, 1024, 0.125f, 0);
    gemm_bt<<<dim3(8, 32, 1), 256, 0, stream>>>(h, 1024, 0, wkT, 1024, 0, 1024,
        bk, nullptr, Kb, nullptr, 1024, 0, 1024, 1.f, 0);
    gemm_bt<<<dim3(8, 32, 1), 256, 0, stream>>>(h, 1024, 0, wvT, 1024, 0, 1024,
        bv, nullptr, Vb, nullptr, 1024, 0, 1024, 1.f, 0);

    // Qrel[h, b*s, p] = Q[:, h*64:+64] @ rel^T   (N=257 padded to 384)
    gemm_bt<<<dim3(3, 32, 16), 256, 0, stream>>>(Qb, 1024, 64, relb, 64, 0, 257,
        nullptr, nullptr, qrel, nullptr, QREL_LD, (long long)4096 * QREL_LD,
        64, 1.f, 0);

    attn_kernel<<<1024, 256, 0, stream>>>(Qb, Kb, Vb, qrel, att);

    // x2 = x + attn @ wo + bo   (fp32)
    gemm_bt<<<dim3(8, 32, 1), 256, 0, stream>>>(att, 1024, 0, woT, 1024, 0, 1024,
        bo, x, nullptr, x2, 1024, 0, 1024, 1.f, 0);

    ln_kernel<<<4096, 256, 0, stream>>>(x2, g2, be2, h2);

    // ff1 = gelu(h2 @ w1 + b1)
    gemm_bt<<<dim3(32, 32, 1), 256, 0, stream>>>(h2, 1024, 0, w1T, 1024, 0, 4096,
        bf1, nullptr, ff1, nullptr, 4096, 0, 1024, 1.f, 1);
    // out = x2 + ff1 @ w2 + b2
    gemm_bt<<<dim3(8, 32, 1), 256, 0, stream>>>(ff1, 4096, 0, w2T, 4096, 0, 1024,
        bf2, x2, nullptr, (float*)d_out, 1024, 0, 4096, 1.f, 0);
}